// Round 21
// baseline (1062.069 us; speedup 1.0000x reference)
//
#include <hip/hip_runtime.h>
#include <hip/hip_bf16.h>

#define Df 384
#define Hf 768
#define SCAN_CH 4096

typedef __bf16 bf16x8 __attribute__((ext_vector_type(8)));
typedef float f32x4 __attribute__((ext_vector_type(4)));

struct __attribute__((aligned(4))) U12 { unsigned int x, y, z; };

__device__ inline unsigned short f2bf(float f) {
    __hip_bfloat16 h = __float2bfloat16(f);
    return __builtin_bit_cast(unsigned short, h);
}
__device__ inline float bf2f(unsigned short u) {
    unsigned int v = ((unsigned int)u) << 16;
    return __builtin_bit_cast(float, v);
}
__device__ inline float lobf(unsigned int v) { return bf2f((unsigned short)(v & 0xffff)); }
__device__ inline float hibf(unsigned int v) { return bf2f((unsigned short)(v >> 16)); }
__device__ inline unsigned int pk2(float a, float b) {
    return (unsigned int)f2bf(a) | ((unsigned int)f2bf(b) << 16);
}
__device__ inline float gelu_(float v) {
    return 0.5f * v * (1.0f + erff(v * 0.70710678118654752f));
}
// direct global->LDS, 16B/lane; LDS dest is WAVE-UNIFORM base, HW adds lane*16.
__device__ inline void gload16(const void* g, void* l) {
    __builtin_amdgcn_global_load_lds(
        (const __attribute__((address_space(1))) unsigned int*)g,
        (__attribute__((address_space(3))) unsigned int*)l, 16, 0, 0);
}

// ---- BN column statistics ----
__global__ void bn_stats(const float* __restrict__ x, float* __restrict__ stats, int N) {
    int t = threadIdx.x;                 // 192 threads
    int c4 = (t % 96) * 4;
    int rs = t / 96;
    float s0 = 0, s1 = 0, s2 = 0, s3 = 0, q0 = 0, q1 = 0, q2 = 0, q3 = 0;
    for (int r = blockIdx.x * 2 + rs; r < N; r += gridDim.x * 2) {
        float4 v = *(const float4*)(x + (size_t)r * Df + c4);
        s0 += v.x; s1 += v.y; s2 += v.z; s3 += v.w;
        q0 += v.x * v.x; q1 += v.y * v.y; q2 += v.z * v.z; q3 += v.w * v.w;
    }
    unsafeAtomicAdd(&stats[c4 + 0], s0);
    unsafeAtomicAdd(&stats[c4 + 1], s1);
    unsafeAtomicAdd(&stats[c4 + 2], s2);
    unsafeAtomicAdd(&stats[c4 + 3], s3);
    unsafeAtomicAdd(&stats[Df + c4 + 0], q0);
    unsafeAtomicAdd(&stats[Df + c4 + 1], q1);
    unsafeAtomicAdd(&stats[Df + c4 + 2], q2);
    unsafeAtomicAdd(&stats[Df + c4 + 3], q3);
}

__global__ void bn_finalize(const float* __restrict__ stats,
                            const float* __restrict__ gamma,
                            const float* __restrict__ beta,
                            float* __restrict__ coef, int N) {
    int c = threadIdx.x; // 384
    float invN = 1.0f / (float)N;
    float mu = stats[c] * invN;
    float var = stats[Df + c] * invN - mu * mu;
    float rs = rsqrtf(var + 1e-5f);
    float a = gamma[c] * rs;
    coef[c] = a;
    coef[Df + c] = beta[c] - mu * a;
}

// ---- h = x*a + b  ->  bf16 ----
__global__ void h_kernel(const float* __restrict__ x, const float* __restrict__ coef,
                         unsigned short* __restrict__ hb, int tot8) {
    int i = blockIdx.x * 256 + threadIdx.x;
    if (i >= tot8) return;
    size_t base = (size_t)i * 8;
    int c = (int)(base % Df);
    float4 x0 = *(const float4*)(x + base);
    float4 x1 = *(const float4*)(x + base + 4);
    const float* a = coef + c;
    const float* b = coef + Df + c;
    uint4 o;
    o.x = pk2(x0.x * a[0] + b[0], x0.y * a[1] + b[1]);
    o.y = pk2(x0.z * a[2] + b[2], x0.w * a[3] + b[3]);
    o.z = pk2(x1.x * a[4] + b[4], x1.y * a[5] + b[5]);
    o.w = pk2(x1.z * a[6] + b[6], x1.w * a[7] + b[7]);
    *(uint4*)(hb + base) = o;
}

// ---- all three weight transposes in one dispatch ----
__global__ void wtrans3(const float* __restrict__ We, const float* __restrict__ W1,
                        const float* __restrict__ W2,
                        unsigned short* __restrict__ WeT, unsigned short* __restrict__ W1T,
                        unsigned short* __restrict__ W2T) {
    int idx = blockIdx.x * 256 + threadIdx.x;
    if (idx < Df * Df) {
        int k = idx / Df, n = idx % Df;
        WeT[n * Df + k] = f2bf(We[idx]);
    } else if (idx < Df * Df + Df * Hf) {
        int i = idx - Df * Df;
        int k = i / Hf, n = i % Hf;
        W1T[(size_t)n * Df + k] = f2bf(W1[i]);
    } else if (idx < Df * Df + 2 * Df * Hf) {
        int i = idx - (Df * Df + Df * Hf);
        int k = i / Df, n = i % Df;
        W2T[(size_t)n * Hf + k] = f2bf(W2[i]);
    }
}

// ---- CSR build ----
__global__ void degree_k(const int* __restrict__ dst, int* __restrict__ deg, int E) {
    int e = blockIdx.x * 256 + threadIdx.x;
    if (e < E) atomicAdd(&deg[dst[e]], 1);
}

__global__ void scan1(const int* __restrict__ deg, int* __restrict__ off,
                      int* __restrict__ sums, int N) {
    __shared__ int ts[256];
    int t = threadIdx.x;
    int base = blockIdx.x * SCAN_CH + t * 16;
    int v[16];
    int s = 0;
    for (int j = 0; j < 16; j++) {
        int idx = base + j;
        int d = (idx < N) ? deg[idx] : 0;
        v[j] = s;
        s += d;
    }
    ts[t] = s;
    __syncthreads();
    for (int o = 1; o < 256; o <<= 1) {
        int add = (t >= o) ? ts[t - o] : 0;
        __syncthreads();
        ts[t] += add;
        __syncthreads();
    }
    int pre = t ? ts[t - 1] : 0;
    for (int j = 0; j < 16; j++) {
        int idx = base + j;
        if (idx < N) off[idx] = pre + v[j];
    }
    if (t == 255) sums[blockIdx.x] = ts[255];
}

__global__ void scan2(int* __restrict__ sums, int nb) {
    int acc = 0;
    for (int b = 0; b < nb; b++) { int v = sums[b]; sums[b] = acc; acc += v; }
    sums[nb] = acc;
}

__global__ void scan3(int* __restrict__ off, const int* __restrict__ sums, int N, int nb) {
    int idx = blockIdx.x * 256 + threadIdx.x;
    if (idx < N) off[idx] += sums[idx / SCAN_CH];
    else if (idx == N) off[N] = sums[nb];
}

// fill: pose[e] = CSR slot of edge e; srcp[slot] = src node of that edge
__global__ void fill_k(const int* __restrict__ dst, const int* __restrict__ src,
                       int* __restrict__ cursor, int* __restrict__ srcp,
                       int* __restrict__ pose, int E) {
    int e = blockIdx.x * 256 + threadIdx.x;
    if (e >= E) return;
    int pos = atomicAdd(&cursor[dst[e]], 1);
    srcp[pos] = src[e];
    pose[e] = pos;
}

// ---- gather-reduce: z[i] = (1+eps)*h[i] + sum relu(msgl[p] + h[srcp[p]]) ----
__global__ __launch_bounds__(256) void aggregate(
    const unsigned short* __restrict__ msgl, const unsigned short* __restrict__ hb,
    const int* __restrict__ off, const int* __restrict__ srcp,
    const float* __restrict__ epsp,
    unsigned short* __restrict__ zb, int N) {
    int lane = threadIdx.x & 63;
    int wid = threadIdx.x >> 6;
    int nwaves = gridDim.x * 4;
    float s1p = 1.0f + epsp[0];
    int loff = lane * 6;
    for (int i = blockIdx.x * 4 + wid; i < N; i += nwaves) {
        int o0 = off[i], o1 = off[i + 1];
        float a0 = 0, a1 = 0, a2 = 0, a3 = 0, a4 = 0, a5 = 0;
        for (int p = o0; p < o1; ++p) {
            int s = srcp[p];
            U12 mv = *(const U12*)(msgl + (size_t)p * Df + loff);
            U12 hv = *(const U12*)(hb + (size_t)s * Df + loff);
            a0 += fmaxf(lobf(mv.x) + lobf(hv.x), 0.f);
            a1 += fmaxf(hibf(mv.x) + hibf(hv.x), 0.f);
            a2 += fmaxf(lobf(mv.y) + lobf(hv.y), 0.f);
            a3 += fmaxf(hibf(mv.y) + hibf(hv.y), 0.f);
            a4 += fmaxf(lobf(mv.z) + lobf(hv.z), 0.f);
            a5 += fmaxf(hibf(mv.z) + hibf(hv.z), 0.f);
        }
        U12 hv = *(const U12*)(hb + (size_t)i * Df + loff);
        U12 o;
        o.x = pk2(s1p * lobf(hv.x) + a0, s1p * hibf(hv.x) + a1);
        o.y = pk2(s1p * lobf(hv.y) + a2, s1p * hibf(hv.y) + a3);
        o.z = pk2(s1p * lobf(hv.z) + a4, s1p * hibf(hv.z) + a5);
        *(U12*)(zb + (size_t)i * Df + loff) = o;
    }
}

// ---- Strip GEMM v2: 256 threads / 4 waves, 64 rows PER WAVE (acc[4][4]) ----
// R20 proved occupancy is not the limiter (65% occ = same 262us); the K-loop
// is a latency-serial chain of 12 load->consume iterations. This doubles the
// output per chain (wave owns 64 rows, 4 independent A loads per k-tile) --
// chains per unit output halve. B-slice LDS-resident (48KB, swizzled);
// barrier-free K-loop; (256,3): cap ~170 regs, 3 blocks/CU.
// EPI 1: bf16 gelu out via LDS-staged full-line stores.
// EPI 2: f32 out = xres + gelu(acc+bias), direct coalesced stores.
template <int KTOT, int EPI>
__global__ __launch_bounds__(256, 3) void gemm_strip(
    const unsigned short* __restrict__ Ab, const unsigned short* __restrict__ Bt,
    const float* __restrict__ bias,
    unsigned short* __restrict__ outb, const float* __restrict__ xres,
    float* __restrict__ outf, int M, int ncols, int ldo) {
    constexpr int NH = KTOT / 384;    // 48KB B halves (1 or 2)
    __shared__ __align__(16) unsigned short Bs[64 * 48 * 8];   // 48 KB

    const int t = threadIdx.x;
    const int nwg = gridDim.x;
    const int orig = blockIdx.x;
    const int xcd = orig & 7;
    const int q = nwg >> 3, r = nwg & 7;
    const int wgid = (xcd < r ? xcd * (q + 1) : r * (q + 1) + (xcd - r) * q) + (orig >> 3);
    const int strip = wgid / ncols;
    const int cb = (wgid - strip * ncols) * 64;

    const int lane = t & 63;
    const int wid = t >> 6;          // 0..3
    const int fr = lane & 15;
    const int kg = lane >> 4;

    auto stageB = [&](int koff) {
#pragma unroll
        for (int s_ = 0; s_ < 12; s_++) {
            int u = s_ * 256 + t;
            int col = u / 48;
            int pos = u - col * 48;
            gload16(Bt + (size_t)(cb + col) * KTOT + koff + ((pos ^ (col & 7)) << 3),
                    &Bs[(s_ * 256 + wid * 64) * 8]);
        }
    };

    int ra0 = strip * 256 + wid * 64 + fr;      if (ra0 >= M) ra0 = M - 1;
    int ra1 = strip * 256 + wid * 64 + 16 + fr; if (ra1 >= M) ra1 = M - 1;
    int ra2 = strip * 256 + wid * 64 + 32 + fr; if (ra2 >= M) ra2 = M - 1;
    int ra3 = strip * 256 + wid * 64 + 48 + fr; if (ra3 >= M) ra3 = M - 1;
    const unsigned short* pA0 = Ab + (size_t)ra0 * KTOT + kg * 8;
    const unsigned short* pA1 = Ab + (size_t)ra1 * KTOT + kg * 8;
    const unsigned short* pA2 = Ab + (size_t)ra2 * KTOT + kg * 8;
    const unsigned short* pA3 = Ab + (size_t)ra3 * KTOT + kg * 8;

    f32x4 acc[4][4];
#pragma unroll
    for (int i = 0; i < 4; i++)
#pragma unroll
        for (int j = 0; j < 4; j++) acc[i][j] = (f32x4){0.f, 0.f, 0.f, 0.f};

    stageB(0);
    asm volatile("s_waitcnt vmcnt(0)" ::: "memory");
    __builtin_amdgcn_s_barrier();

#pragma unroll
    for (int h = 0; h < NH; h++) {
        if (h > 0) {
            __syncthreads();
            stageB(h * 384);
            asm volatile("s_waitcnt vmcnt(0)" ::: "memory");
            __builtin_amdgcn_s_barrier();
        }
#pragma unroll
        for (int ktl = 0; ktl < 12; ktl++) {
            const int kt = h * 12 + ktl;
            uint4 a0 = *(const uint4*)(pA0 + kt * 32);
            uint4 a1 = *(const uint4*)(pA1 + kt * 32);
            uint4 a2 = *(const uint4*)(pA2 + kt * 32);
            uint4 a3 = *(const uint4*)(pA3 + kt * 32);
            bf16x8 bfv[4];
#pragma unroll
            for (int j = 0; j < 4; j++) {
                const int cl = j * 16 + fr;
                const int unit = (ktl * 4 + kg) ^ (cl & 7);
                bfv[j] = *(const bf16x8*)&Bs[(cl * 48 + unit) * 8];
            }
            bf16x8 av0 = __builtin_bit_cast(bf16x8, a0);
            bf16x8 av1 = __builtin_bit_cast(bf16x8, a1);
            bf16x8 av2 = __builtin_bit_cast(bf16x8, a2);
            bf16x8 av3 = __builtin_bit_cast(bf16x8, a3);
#pragma unroll
            for (int j = 0; j < 4; j++) {
                acc[0][j] = __builtin_amdgcn_mfma_f32_16x16x32_bf16(av0, bfv[j], acc[0][j], 0, 0, 0);
                acc[1][j] = __builtin_amdgcn_mfma_f32_16x16x32_bf16(av1, bfv[j], acc[1][j], 0, 0, 0);
                acc[2][j] = __builtin_amdgcn_mfma_f32_16x16x32_bf16(av2, bfv[j], acc[2][j], 0, 0, 0);
                acc[3][j] = __builtin_amdgcn_mfma_f32_16x16x32_bf16(av3, bfv[j], acc[3][j], 0, 0, 0);
            }
        }
    }

    float bv[4];
#pragma unroll
    for (int j = 0; j < 4; j++) bv[j] = bias[cb + j * 16 + fr];
    const int kg4 = kg * 4;
    const int rbase = strip * 256;

    if (EPI == 1) {
        // stage C through dead B-LDS (256 rows x 72-short stride = 36KB)
        __syncthreads();
        unsigned short* Ct = Bs;
#pragma unroll
        for (int i = 0; i < 4; i++) {
            const int rl = wid * 64 + i * 16 + kg4;
#pragma unroll
            for (int j = 0; j < 4; j++) {
#pragma unroll
                for (int rr = 0; rr < 4; rr++)
                    Ct[(rl + rr) * 72 + j * 16 + fr] = f2bf(gelu_(acc[i][j][rr] + bv[j]));
            }
        }
        __syncthreads();
#pragma unroll
        for (int s_ = 0; s_ < 8; s_++) {
            int u = s_ * 256 + t;
            int rl = u >> 3, seg = u & 7;
            int grow = rbase + rl;
            if (grow < M)
                *(uint4*)(outb + (size_t)grow * ldo + cb + seg * 8) =
                    *(const uint4*)&Ct[rl * 72 + seg * 8];
        }
    } else {
#pragma unroll
        for (int i = 0; i < 4; i++) {
            const int rb = rbase + wid * 64 + i * 16 + kg4;
#pragma unroll
            for (int rr = 0; rr < 4; rr++) {
                const int row = rb + rr;
                if (row < M) {
#pragma unroll
                    for (int j = 0; j < 4; j++) {
                        size_t o = (size_t)row * ldo + cb + j * 16 + fr;
                        outf[o] = xres[o] + gelu_(acc[i][j][rr] + bv[j]);
                    }
                }
            }
        }
    }
}

// ---- Edge strip GEMM v2 (f32 A): 256 threads / 4 waves, 64 rows per wave ----
__global__ __launch_bounds__(256, 3) void gemm_edge(
    const float* __restrict__ Af, const unsigned short* __restrict__ Bt,
    const float* __restrict__ bias, const int* __restrict__ pose,
    unsigned short* __restrict__ outb, int M) {
    __shared__ __align__(16) unsigned short Bs[64 * 48 * 8];   // 48 KB

    const int t = threadIdx.x;
    const int nwg = gridDim.x;
    const int orig = blockIdx.x;
    const int xcd = orig & 7;
    const int q = nwg >> 3, r = nwg & 7;
    const int wgid = (xcd < r ? xcd * (q + 1) : r * (q + 1) + (xcd - r) * q) + (orig >> 3);
    const int strip = wgid / 6;
    const int cb = (wgid - strip * 6) * 64;

    const int lane = t & 63;
    const int wid = t >> 6;
    const int fr = lane & 15;
    const int kg = lane >> 4;

#pragma unroll
    for (int s_ = 0; s_ < 12; s_++) {
        int u = s_ * 256 + t;
        int col = u / 48;
        int pos = u - col * 48;
        gload16(Bt + (size_t)(cb + col) * Df + ((pos ^ (col & 7)) << 3),
                &Bs[(s_ * 256 + wid * 64) * 8]);
    }

    int ra0 = strip * 256 + wid * 64 + fr;      if (ra0 >= M) ra0 = M - 1;
    int ra1 = strip * 256 + wid * 64 + 16 + fr; if (ra1 >= M) ra1 = M - 1;
    int ra2 = strip * 256 + wid * 64 + 32 + fr; if (ra2 >= M) ra2 = M - 1;
    int ra3 = strip * 256 + wid * 64 + 48 + fr; if (ra3 >= M) ra3 = M - 1;
    const float* pA0 = Af + (size_t)ra0 * Df + kg * 8;
    const float* pA1 = Af + (size_t)ra1 * Df + kg * 8;
    const float* pA2 = Af + (size_t)ra2 * Df + kg * 8;
    const float* pA3 = Af + (size_t)ra3 * Df + kg * 8;

    f32x4 acc[4][4];
#pragma unroll
    for (int i = 0; i < 4; i++)
#pragma unroll
        for (int j = 0; j < 4; j++) acc[i][j] = (f32x4){0.f, 0.f, 0.f, 0.f};

    asm volatile("s_waitcnt vmcnt(0)" ::: "memory");
    __builtin_amdgcn_s_barrier();

#pragma unroll
    for (int kt = 0; kt < 12; kt++) {
        uint4 a0l = *(const uint4*)(pA0 + kt * 32);
        uint4 a0h = *(const uint4*)(pA0 + kt * 32 + 4);
        uint4 a1l = *(const uint4*)(pA1 + kt * 32);
        uint4 a1h = *(const uint4*)(pA1 + kt * 32 + 4);
        uint4 a2l = *(const uint4*)(pA2 + kt * 32);
        uint4 a2h = *(const uint4*)(pA2 + kt * 32 + 4);
        uint4 a3l = *(const uint4*)(pA3 + kt * 32);
        uint4 a3h = *(const uint4*)(pA3 + kt * 32 + 4);
        bf16x8 bfv[4];
#pragma unroll
        for (int j = 0; j < 4; j++) {
            const int cl = j * 16 + fr;
            const int unit = (kt * 4 + kg) ^ (cl & 7);
            bfv[j] = *(const bf16x8*)&Bs[(cl * 48 + unit) * 8];
        }
#pragma unroll
        for (int i = 0; i < 4; i++) {
            uint4 lo, hi;
            if (i == 0) { lo = a0l; hi = a0h; }
            else if (i == 1) { lo = a1l; hi = a1h; }
            else if (i == 2) { lo = a2l; hi = a2h; }
            else { lo = a3l; hi = a3h; }
            float4 x0 = __builtin_bit_cast(float4, lo);
            float4 x1 = __builtin_bit_cast(float4, hi);
            uint4 u;
            u.x = pk2(x0.x, x0.y); u.y = pk2(x0.z, x0.w);
            u.z = pk2(x1.x, x1.y); u.w = pk2(x1.z, x1.w);
            bf16x8 av = __builtin_bit_cast(bf16x8, u);
#pragma unroll
            for (int j = 0; j < 4; j++)
                acc[i][j] = __builtin_amdgcn_mfma_f32_16x16x32_bf16(av, bfv[j], acc[i][j], 0, 0, 0);
        }
    }

    float bv[4];
#pragma unroll
    for (int j = 0; j < 4; j++) bv[j] = bias[cb + j * 16 + fr];
    const int kg4 = kg * 4;
    const int rbase = strip * 256;

    __syncthreads();
    unsigned short* Ct = Bs;
#pragma unroll
    for (int i = 0; i < 4; i++) {
        const int rl = wid * 64 + i * 16 + kg4;
#pragma unroll
        for (int j = 0; j < 4; j++) {
#pragma unroll
            for (int rr = 0; rr < 4; rr++)
                Ct[(rl + rr) * 72 + j * 16 + fr] = f2bf(acc[i][j][rr] + bv[j]);
        }
    }
    __syncthreads();
#pragma unroll
    for (int s_ = 0; s_ < 8; s_++) {
        int u = s_ * 256 + t;
        int rl = u >> 3, seg = u & 7;
        int grow = rbase + rl;
        if (grow < M)
            *(uint4*)(outb + (size_t)pose[grow] * Df + cb + seg * 8) =
                *(const uint4*)&Ct[rl * 72 + seg * 8];
    }
}

extern "C" void kernel_launch(void* const* d_in, const int* in_sizes, int n_in,
                              void* d_out, int out_size, void* d_ws, size_t ws_size,
                              hipStream_t stream) {
    const float* x = (const float*)d_in[0];
    const float* ea = (const float*)d_in[1];
    const float* gamma = (const float*)d_in[2];
    const float* beta = (const float*)d_in[3];
    const float* epsp = (const float*)d_in[4];
    const float* W_edge = (const float*)d_in[5];
    const float* b_edge = (const float*)d_in[6];
    const float* W1 = (const float*)d_in[7];
    const float* b1 = (const float*)d_in[8];
    const float* W2 = (const float*)d_in[9];
    const float* b2 = (const float*)d_in[10];
    const int* eidx = (const int*)d_in[11];
    float* out = (float*)d_out;
    const int N = in_sizes[0] / Df;
    const int E = in_sizes[1] / Df;
    const int* esrc = eidx;
    const int* edst = eidx + E;

    char* w = (char*)d_ws;
    size_t off_ = 0;
    auto alloc = [&](size_t bytes) { char* p = w + off_; off_ += (bytes + 255) & ~(size_t)255; return p; };
    float* stats = (float*)alloc(2 * Df * sizeof(float));
    float* coef = (float*)alloc(2 * Df * sizeof(float));
    unsigned short* hb = (unsigned short*)alloc((size_t)N * Df * 2);
    unsigned short* zb = (unsigned short*)alloc((size_t)N * Df * 2);
    unsigned short* tb = (unsigned short*)alloc((size_t)N * Hf * 2);
    unsigned short* WeT = (unsigned short*)alloc((size_t)Df * Df * 2);
    unsigned short* W1T = (unsigned short*)alloc((size_t)Df * Hf * 2);
    unsigned short* W2T = (unsigned short*)alloc((size_t)Hf * Df * 2);
    int* deg = (int*)alloc((size_t)(N + 1) * 4);      // reused as fill cursor
    int* offs = (int*)alloc((size_t)(N + 1) * 4);
    int* srcp = (int*)alloc((size_t)E * 4);
    int* pose = (int*)alloc((size_t)E * 4);
    int* sums = (int*)alloc(64 * 4);
    size_t msgl_bytes = (size_t)E * Df * 2;
    unsigned short* msgl;
    if (off_ + msgl_bytes <= ws_size) msgl = (unsigned short*)alloc(msgl_bytes);
    else msgl = (unsigned short*)d_out;   // dead until final GEMM writes it
    (void)n_in; (void)out_size;

    hipMemsetAsync(stats, 0, 2 * Df * sizeof(float), stream);
    hipMemsetAsync(deg, 0, (size_t)N * 4, stream);

    // BN + h
    bn_stats<<<1024, 192, 0, stream>>>(x, stats, N);
    bn_finalize<<<1, Df, 0, stream>>>(stats, gamma, beta, coef, N);
    int tot8 = N * Df / 8;
    h_kernel<<<(tot8 + 255) / 256, 256, 0, stream>>>(x, coef, hb, tot8);

    // weights (one dispatch)
    wtrans3<<<(Df * Df + 2 * Df * Hf + 255) / 256, 256, 0, stream>>>(
        W_edge, W1, W2, WeT, W1T, W2T);

    // CSR by dst
    int nb = (N + SCAN_CH - 1) / SCAN_CH;
    degree_k<<<(E + 255) / 256, 256, 0, stream>>>(edst, deg, E);
    scan1<<<nb, 256, 0, stream>>>(deg, offs, sums, N);
    scan2<<<1, 1, 0, stream>>>(sums, nb);
    scan3<<<(N + 256) / 256, 256, 0, stream>>>(offs, sums, N, nb);
    hipMemcpyAsync(deg, offs, (size_t)N * 4, hipMemcpyDeviceToDevice, stream);
    fill_k<<<(E + 255) / 256, 256, 0, stream>>>(edst, esrc, deg, srcp, pose, E);

    // edge linear (strip-v2, f32 A): msgl[pose[e]] = ea[e] @ We^T + b_edge
    int estrips = (E + 255) / 256;
    gemm_edge<<<dim3(estrips * 6), 256, 0, stream>>>(ea, WeT, b_edge, pose, msgl, E);

    // gather-reduce -> z (bf16)
    aggregate<<<2048, 256, 0, stream>>>(msgl, hb, offs, srcp, epsp, zb, N);

    // GEMM1 (strip-v2): tb = bf16(gelu(zb @ W1T^T + b1))
    int strips = (N + 255) / 256;
    gemm_strip<Df, 1><<<dim3(strips * (Hf / 64)), 256, 0, stream>>>(
        zb, W1T, b1, tb, nullptr, nullptr, N, Hf / 64, Hf);

    // GEMM2 (strip-v2, K=768 two halves): out = x + gelu(tb @ W2T^T + b2)
    gemm_strip<Hf, 2><<<dim3(strips * (Df / 64)), 256, 0, stream>>>(
        tb, W2T, b2, nullptr, x, out, N, Df / 64, Df);
}

// Round 22
// 984.626 us; speedup vs baseline: 1.0787x; 1.0787x over previous
//
#include <hip/hip_runtime.h>
#include <hip/hip_bf16.h>

#define Df 384
#define Hf 768
#define SCAN_CH 4096

typedef __bf16 bf16x8 __attribute__((ext_vector_type(8)));
typedef float f32x4 __attribute__((ext_vector_type(4)));

struct __attribute__((aligned(4))) U12 { unsigned int x, y, z; };

__device__ inline unsigned short f2bf(float f) {
    __hip_bfloat16 h = __float2bfloat16(f);
    return __builtin_bit_cast(unsigned short, h);
}
__device__ inline float bf2f(unsigned short u) {
    unsigned int v = ((unsigned int)u) << 16;
    return __builtin_bit_cast(float, v);
}
__device__ inline float lobf(unsigned int v) { return bf2f((unsigned short)(v & 0xffff)); }
__device__ inline float hibf(unsigned int v) { return bf2f((unsigned short)(v >> 16)); }
__device__ inline unsigned int pk2(float a, float b) {
    return (unsigned int)f2bf(a) | ((unsigned int)f2bf(b) << 16);
}
__device__ inline float gelu_(float v) {
    return 0.5f * v * (1.0f + erff(v * 0.70710678118654752f));
}
// direct global->LDS, 16B/lane; LDS dest is WAVE-UNIFORM base, HW adds lane*16.
__device__ inline void gload16(const void* g, void* l) {
    __builtin_amdgcn_global_load_lds(
        (const __attribute__((address_space(1))) unsigned int*)g,
        (__attribute__((address_space(3))) unsigned int*)l, 16, 0, 0);
}

// ---- BN column statistics ----
__global__ void bn_stats(const float* __restrict__ x, float* __restrict__ stats, int N) {
    int t = threadIdx.x;                 // 192 threads
    int c4 = (t % 96) * 4;
    int rs = t / 96;
    float s0 = 0, s1 = 0, s2 = 0, s3 = 0, q0 = 0, q1 = 0, q2 = 0, q3 = 0;
    for (int r = blockIdx.x * 2 + rs; r < N; r += gridDim.x * 2) {
        float4 v = *(const float4*)(x + (size_t)r * Df + c4);
        s0 += v.x; s1 += v.y; s2 += v.z; s3 += v.w;
        q0 += v.x * v.x; q1 += v.y * v.y; q2 += v.z * v.z; q3 += v.w * v.w;
    }
    unsafeAtomicAdd(&stats[c4 + 0], s0);
    unsafeAtomicAdd(&stats[c4 + 1], s1);
    unsafeAtomicAdd(&stats[c4 + 2], s2);
    unsafeAtomicAdd(&stats[c4 + 3], s3);
    unsafeAtomicAdd(&stats[Df + c4 + 0], q0);
    unsafeAtomicAdd(&stats[Df + c4 + 1], q1);
    unsafeAtomicAdd(&stats[Df + c4 + 2], q2);
    unsafeAtomicAdd(&stats[Df + c4 + 3], q3);
}

__global__ void bn_finalize(const float* __restrict__ stats,
                            const float* __restrict__ gamma,
                            const float* __restrict__ beta,
                            float* __restrict__ coef, int N) {
    int c = threadIdx.x; // 384
    float invN = 1.0f / (float)N;
    float mu = stats[c] * invN;
    float var = stats[Df + c] * invN - mu * mu;
    float rs = rsqrtf(var + 1e-5f);
    float a = gamma[c] * rs;
    coef[c] = a;
    coef[Df + c] = beta[c] - mu * a;
}

// ---- h = x*a + b  ->  bf16 ----
__global__ void h_kernel(const float* __restrict__ x, const float* __restrict__ coef,
                         unsigned short* __restrict__ hb, int tot8) {
    int i = blockIdx.x * 256 + threadIdx.x;
    if (i >= tot8) return;
    size_t base = (size_t)i * 8;
    int c = (int)(base % Df);
    float4 x0 = *(const float4*)(x + base);
    float4 x1 = *(const float4*)(x + base + 4);
    const float* a = coef + c;
    const float* b = coef + Df + c;
    uint4 o;
    o.x = pk2(x0.x * a[0] + b[0], x0.y * a[1] + b[1]);
    o.y = pk2(x0.z * a[2] + b[2], x0.w * a[3] + b[3]);
    o.z = pk2(x1.x * a[4] + b[4], x1.y * a[5] + b[5]);
    o.w = pk2(x1.z * a[6] + b[6], x1.w * a[7] + b[7]);
    *(uint4*)(hb + base) = o;
}

// ---- all three weight transposes in one dispatch ----
__global__ void wtrans3(const float* __restrict__ We, const float* __restrict__ W1,
                        const float* __restrict__ W2,
                        unsigned short* __restrict__ WeT, unsigned short* __restrict__ W1T,
                        unsigned short* __restrict__ W2T) {
    int idx = blockIdx.x * 256 + threadIdx.x;
    if (idx < Df * Df) {
        int k = idx / Df, n = idx % Df;
        WeT[n * Df + k] = f2bf(We[idx]);
    } else if (idx < Df * Df + Df * Hf) {
        int i = idx - Df * Df;
        int k = i / Hf, n = i % Hf;
        W1T[(size_t)n * Df + k] = f2bf(W1[i]);
    } else if (idx < Df * Df + 2 * Df * Hf) {
        int i = idx - (Df * Df + Df * Hf);
        int k = i / Df, n = i % Df;
        W2T[(size_t)n * Hf + k] = f2bf(W2[i]);
    }
}

// ---- CSR build ----
__global__ void degree_k(const int* __restrict__ dst, int* __restrict__ deg, int E) {
    int e = blockIdx.x * 256 + threadIdx.x;
    if (e < E) atomicAdd(&deg[dst[e]], 1);
}

__global__ void scan1(const int* __restrict__ deg, int* __restrict__ off,
                      int* __restrict__ sums, int N) {
    __shared__ int ts[256];
    int t = threadIdx.x;
    int base = blockIdx.x * SCAN_CH + t * 16;
    int v[16];
    int s = 0;
    for (int j = 0; j < 16; j++) {
        int idx = base + j;
        int d = (idx < N) ? deg[idx] : 0;
        v[j] = s;
        s += d;
    }
    ts[t] = s;
    __syncthreads();
    for (int o = 1; o < 256; o <<= 1) {
        int add = (t >= o) ? ts[t - o] : 0;
        __syncthreads();
        ts[t] += add;
        __syncthreads();
    }
    int pre = t ? ts[t - 1] : 0;
    for (int j = 0; j < 16; j++) {
        int idx = base + j;
        if (idx < N) off[idx] = pre + v[j];
    }
    if (t == 255) sums[blockIdx.x] = ts[255];
}

__global__ void scan2(int* __restrict__ sums, int nb) {
    int acc = 0;
    for (int b = 0; b < nb; b++) { int v = sums[b]; sums[b] = acc; acc += v; }
    sums[nb] = acc;
}

__global__ void scan3(int* __restrict__ off, const int* __restrict__ sums, int N, int nb) {
    int idx = blockIdx.x * 256 + threadIdx.x;
    if (idx < N) off[idx] += sums[idx / SCAN_CH];
    else if (idx == N) off[N] = sums[nb];
}

// fill: pose[e] = CSR slot of edge e; srcp[slot] = src node of that edge
__global__ void fill_k(const int* __restrict__ dst, const int* __restrict__ src,
                       int* __restrict__ cursor, int* __restrict__ srcp,
                       int* __restrict__ pose, int E) {
    int e = blockIdx.x * 256 + threadIdx.x;
    if (e >= E) return;
    int pos = atomicAdd(&cursor[dst[e]], 1);
    srcp[pos] = src[e];
    pose[e] = pos;
}

// ---- gather-reduce: z[i] = (1+eps)*h[i] + sum relu(msgl[p] + h[srcp[p]]) ----
__global__ __launch_bounds__(256) void aggregate(
    const unsigned short* __restrict__ msgl, const unsigned short* __restrict__ hb,
    const int* __restrict__ off, const int* __restrict__ srcp,
    const float* __restrict__ epsp,
    unsigned short* __restrict__ zb, int N) {
    int lane = threadIdx.x & 63;
    int wid = threadIdx.x >> 6;
    int nwaves = gridDim.x * 4;
    float s1p = 1.0f + epsp[0];
    int loff = lane * 6;
    for (int i = blockIdx.x * 4 + wid; i < N; i += nwaves) {
        int o0 = off[i], o1 = off[i + 1];
        float a0 = 0, a1 = 0, a2 = 0, a3 = 0, a4 = 0, a5 = 0;
        for (int p = o0; p < o1; ++p) {
            int s = srcp[p];
            U12 mv = *(const U12*)(msgl + (size_t)p * Df + loff);
            U12 hv = *(const U12*)(hb + (size_t)s * Df + loff);
            a0 += fmaxf(lobf(mv.x) + lobf(hv.x), 0.f);
            a1 += fmaxf(hibf(mv.x) + hibf(hv.x), 0.f);
            a2 += fmaxf(lobf(mv.y) + lobf(hv.y), 0.f);
            a3 += fmaxf(hibf(mv.y) + hibf(hv.y), 0.f);
            a4 += fmaxf(lobf(mv.z) + lobf(hv.z), 0.f);
            a5 += fmaxf(hibf(mv.z) + hibf(hv.z), 0.f);
        }
        U12 hv = *(const U12*)(hb + (size_t)i * Df + loff);
        U12 o;
        o.x = pk2(s1p * lobf(hv.x) + a0, s1p * hibf(hv.x) + a1);
        o.y = pk2(s1p * lobf(hv.y) + a2, s1p * hibf(hv.y) + a3);
        o.z = pk2(s1p * lobf(hv.z) + a4, s1p * hibf(hv.z) + a5);
        *(U12*)(zb + (size_t)i * Df + loff) = o;
    }
}

// ---- Strip GEMM, 512 threads (8 waves) on 256-row strips x 64-col slice ----
// launch_bounds(512,4): VGPR cap 128 (no spill). 2 blocks/CU = 16 waves/CU.
// Barrier-free K-loop, depth-3 A rotation (best measured config, R17: 987us).
// EPI 1: bf16 gelu out via LDS-staged full-line stores.
// EPI 2: f32 out = xres + gelu(acc+bias), direct coalesced stores.
template <int KTOT, int EPI>
__global__ __launch_bounds__(512, 4) void gemm_strip(
    const unsigned short* __restrict__ Ab, const unsigned short* __restrict__ Bt,
    const float* __restrict__ bias,
    unsigned short* __restrict__ outb, const float* __restrict__ xres,
    float* __restrict__ outf, int M, int ncols, int ldo) {
    constexpr int NKT = KTOT / 32;    // total k-tiles (12 or 24)
    constexpr int NH = KTOT / 384;    // 48KB B halves (1 or 2)
    __shared__ __align__(16) unsigned short Bs[64 * 48 * 8];   // 48 KB

    const int t = threadIdx.x;
    const int nwg = gridDim.x;
    const int orig = blockIdx.x;
    const int xcd = orig & 7;
    const int q = nwg >> 3, r = nwg & 7;
    const int wgid = (xcd < r ? xcd * (q + 1) : r * (q + 1) + (xcd - r) * q) + (orig >> 3);
    const int strip = wgid / ncols;
    const int cb = (wgid - strip * ncols) * 64;

    const int lane = t & 63;
    const int wid = t >> 6;          // 0..7
    const int fr = lane & 15;
    const int kg = lane >> 4;

    auto stageB = [&](int koff) {
#pragma unroll
        for (int s_ = 0; s_ < 6; s_++) {
            int u = s_ * 512 + t;
            int col = u / 48;
            int pos = u - col * 48;
            gload16(Bt + (size_t)(cb + col) * KTOT + koff + ((pos ^ (col & 7)) << 3),
                    &Bs[(s_ * 512 + wid * 64) * 8]);
        }
    };

    int ra0 = strip * 256 + wid * 32 + fr;      if (ra0 >= M) ra0 = M - 1;
    int ra1 = strip * 256 + wid * 32 + 16 + fr; if (ra1 >= M) ra1 = M - 1;
    const unsigned short* pA0 = Ab + (size_t)ra0 * KTOT + kg * 8;
    const unsigned short* pA1 = Ab + (size_t)ra1 * KTOT + kg * 8;

    f32x4 acc[2][4];
#pragma unroll
    for (int i = 0; i < 2; i++)
#pragma unroll
        for (int j = 0; j < 4; j++) acc[i][j] = (f32x4){0.f, 0.f, 0.f, 0.f};

    stageB(0);
    uint4 p0a = *(const uint4*)(pA0);       uint4 p0b = *(const uint4*)(pA1);
    uint4 p1a = *(const uint4*)(pA0 + 32);  uint4 p1b = *(const uint4*)(pA1 + 32);
    uint4 p2a = *(const uint4*)(pA0 + 64);  uint4 p2b = *(const uint4*)(pA1 + 64);
    asm volatile("s_waitcnt vmcnt(0)" ::: "memory");
    __builtin_amdgcn_s_barrier();

#define STEP(kt_, ktl_, pa_, pb_) do {                                          \
        bf16x8 bfv[4];                                                          \
        _Pragma("unroll")                                                       \
        for (int j_ = 0; j_ < 4; j_++) {                                        \
            const int cl_ = j_ * 16 + fr;                                       \
            const int unit_ = ((ktl_) * 4 + kg) ^ (cl_ & 7);                    \
            bfv[j_] = *(const bf16x8*)&Bs[(cl_ * 48 + unit_) * 8];              \
        }                                                                       \
        bf16x8 av0_ = __builtin_bit_cast(bf16x8, pa_);                          \
        bf16x8 av1_ = __builtin_bit_cast(bf16x8, pb_);                          \
        if ((kt_) + 3 < NKT) {                                                  \
            pa_ = *(const uint4*)(pA0 + ((kt_) + 3) * 32);                      \
            pb_ = *(const uint4*)(pA1 + ((kt_) + 3) * 32);                      \
        }                                                                       \
        _Pragma("unroll")                                                       \
        for (int j_ = 0; j_ < 4; j_++) {                                        \
            acc[0][j_] = __builtin_amdgcn_mfma_f32_16x16x32_bf16(av0_, bfv[j_], acc[0][j_], 0, 0, 0); \
            acc[1][j_] = __builtin_amdgcn_mfma_f32_16x16x32_bf16(av1_, bfv[j_], acc[1][j_], 0, 0, 0); \
        }                                                                       \
    } while (0)

#pragma unroll
    for (int h = 0; h < NH; h++) {
        if (h > 0) {
            __syncthreads();
            stageB(h * 384);
            asm volatile("s_waitcnt vmcnt(0)" ::: "memory");
            __builtin_amdgcn_s_barrier();
        }
#pragma unroll
        for (int kq = 0; kq < 4; kq++) {
            STEP(h * 12 + kq * 3 + 0, kq * 3 + 0, p0a, p0b);
            STEP(h * 12 + kq * 3 + 1, kq * 3 + 1, p1a, p1b);
            STEP(h * 12 + kq * 3 + 2, kq * 3 + 2, p2a, p2b);
        }
    }
#undef STEP

    float bv[4];
#pragma unroll
    for (int j = 0; j < 4; j++) bv[j] = bias[cb + j * 16 + fr];
    const int kg4 = kg * 4;
    const int rbase = strip * 256;

    if (EPI == 1) {
        // stage C through dead B-LDS (256 rows x 72-short stride = 36KB)
        __syncthreads();
        unsigned short* Ct = Bs;
#pragma unroll
        for (int i = 0; i < 2; i++) {
            const int rl = wid * 32 + i * 16 + kg4;
#pragma unroll
            for (int j = 0; j < 4; j++) {
#pragma unroll
                for (int rr = 0; rr < 4; rr++)
                    Ct[(rl + rr) * 72 + j * 16 + fr] = f2bf(gelu_(acc[i][j][rr] + bv[j]));
            }
        }
        __syncthreads();
#pragma unroll
        for (int s_ = 0; s_ < 4; s_++) {
            int u = s_ * 512 + t;
            int rl = u >> 3, seg = u & 7;
            int grow = rbase + rl;
            if (grow < M)
                *(uint4*)(outb + (size_t)grow * ldo + cb + seg * 8) =
                    *(const uint4*)&Ct[rl * 72 + seg * 8];
        }
    } else {
#pragma unroll
        for (int i = 0; i < 2; i++) {
            const int rb = rbase + wid * 32 + i * 16 + kg4;
#pragma unroll
            for (int rr = 0; rr < 4; rr++) {
                const int row = rb + rr;
                if (row < M) {
#pragma unroll
                    for (int j = 0; j < 4; j++) {
                        size_t o = (size_t)row * ldo + cb + j * 16 + fr;
                        outf[o] = xres[o] + gelu_(acc[i][j][rr] + bv[j]);
                    }
                }
            }
        }
    }
}

// ---- Edge strip GEMM, 512 threads (f32 A): msgl[pose[row]] = bf16(A@We^T + b) ----
__global__ __launch_bounds__(512, 4) void gemm_edge(
    const float* __restrict__ Af, const unsigned short* __restrict__ Bt,
    const float* __restrict__ bias, const int* __restrict__ pose,
    unsigned short* __restrict__ outb, int M) {
    __shared__ __align__(16) unsigned short Bs[64 * 48 * 8];   // 48 KB

    const int t = threadIdx.x;
    const int nwg = gridDim.x;
    const int orig = blockIdx.x;
    const int xcd = orig & 7;
    const int q = nwg >> 3, r = nwg & 7;
    const int wgid = (xcd < r ? xcd * (q + 1) : r * (q + 1) + (xcd - r) * q) + (orig >> 3);
    const int strip = wgid / 6;
    const int cb = (wgid - strip * 6) * 64;

    const int lane = t & 63;
    const int wid = t >> 6;
    const int fr = lane & 15;
    const int kg = lane >> 4;

#pragma unroll
    for (int s_ = 0; s_ < 6; s_++) {
        int u = s_ * 512 + t;
        int col = u / 48;
        int pos = u - col * 48;
        gload16(Bt + (size_t)(cb + col) * Df + ((pos ^ (col & 7)) << 3),
                &Bs[(s_ * 512 + wid * 64) * 8]);
    }

    int ra0 = strip * 256 + wid * 32 + fr;      if (ra0 >= M) ra0 = M - 1;
    int ra1 = strip * 256 + wid * 32 + 16 + fr; if (ra1 >= M) ra1 = M - 1;
    const float* pA0 = Af + (size_t)ra0 * Df + kg * 8;
    const float* pA1 = Af + (size_t)ra1 * Df + kg * 8;

    f32x4 acc[2][4];
#pragma unroll
    for (int i = 0; i < 2; i++)
#pragma unroll
        for (int j = 0; j < 4; j++) acc[i][j] = (f32x4){0.f, 0.f, 0.f, 0.f};

    uint4 p0al = *(const uint4*)(pA0);       uint4 p0ah = *(const uint4*)(pA0 + 4);
    uint4 p0bl = *(const uint4*)(pA1);       uint4 p0bh = *(const uint4*)(pA1 + 4);
    uint4 p1al = *(const uint4*)(pA0 + 32);  uint4 p1ah = *(const uint4*)(pA0 + 36);
    uint4 p1bl = *(const uint4*)(pA1 + 32);  uint4 p1bh = *(const uint4*)(pA1 + 36);
    uint4 p2al = *(const uint4*)(pA0 + 64);  uint4 p2ah = *(const uint4*)(pA0 + 68);
    uint4 p2bl = *(const uint4*)(pA1 + 64);  uint4 p2bh = *(const uint4*)(pA1 + 68);
    asm volatile("s_waitcnt vmcnt(0)" ::: "memory");
    __builtin_amdgcn_s_barrier();

#define ESTEP(kt_, pal_, pah_, pbl_, pbh_) do {                                 \
        bf16x8 bfv[4];                                                          \
        _Pragma("unroll")                                                       \
        for (int j_ = 0; j_ < 4; j_++) {                                        \
            const int cl_ = j_ * 16 + fr;                                       \
            const int unit_ = ((kt_) * 4 + kg) ^ (cl_ & 7);                     \
            bfv[j_] = *(const bf16x8*)&Bs[(cl_ * 48 + unit_) * 8];              \
        }                                                                       \
        float4 xa0_ = __builtin_bit_cast(float4, pal_);                         \
        float4 xa1_ = __builtin_bit_cast(float4, pah_);                         \
        uint4 ua_;                                                              \
        ua_.x = pk2(xa0_.x, xa0_.y); ua_.y = pk2(xa0_.z, xa0_.w);               \
        ua_.z = pk2(xa1_.x, xa1_.y); ua_.w = pk2(xa1_.z, xa1_.w);               \
        bf16x8 av0_ = __builtin_bit_cast(bf16x8, ua_);                          \
        float4 xb0_ = __builtin_bit_cast(float4, pbl_);                         \
        float4 xb1_ = __builtin_bit_cast(float4, pbh_);                         \
        uint4 ub_;                                                              \
        ub_.x = pk2(xb0_.x, xb0_.y); ub_.y = pk2(xb0_.z, xb0_.w);               \
        ub_.z = pk2(xb1_.x, xb1_.y); ub_.w = pk2(xb1_.z, xb1_.w);               \
        bf16x8 av1_ = __builtin_bit_cast(bf16x8, ub_);                          \
        if ((kt_) + 3 < 12) {                                                   \
            pal_ = *(const uint4*)(pA0 + ((kt_) + 3) * 32);                     \
            pah_ = *(const uint4*)(pA0 + ((kt_) + 3) * 32 + 4);                 \
            pbl_ = *(const uint4*)(pA1 + ((kt_) + 3) * 32);                     \
            pbh_ = *(const uint4*)(pA1 + ((kt_) + 3) * 32 + 4);                 \
        }                                                                       \
        _Pragma("unroll")                                                       \
        for (int j_ = 0; j_ < 4; j_++) {                                        \
            acc[0][j_] = __builtin_amdgcn_mfma_f32_16x16x32_bf16(av0_, bfv[j_], acc[0][j_], 0, 0, 0); \
            acc[1][j_] = __builtin_amdgcn_mfma_f32_16x16x32_bf16(av1_, bfv[j_], acc[1][j_], 0, 0, 0); \
        }                                                                       \
    } while (0)

#pragma unroll
    for (int kq = 0; kq < 4; kq++) {
        ESTEP(kq * 3 + 0, p0al, p0ah, p0bl, p0bh);
        ESTEP(kq * 3 + 1, p1al, p1ah, p1bl, p1bh);
        ESTEP(kq * 3 + 2, p2al, p2ah, p2bl, p2bh);
    }
#undef ESTEP

    float bv[4];
#pragma unroll
    for (int j = 0; j < 4; j++) bv[j] = bias[cb + j * 16 + fr];
    const int kg4 = kg * 4;
    const int rbase = strip * 256;

    __syncthreads();
    unsigned short* Ct = Bs;
#pragma unroll
    for (int i = 0; i < 2; i++) {
        const int rl = wid * 32 + i * 16 + kg4;
#pragma unroll
        for (int j = 0; j < 4; j++) {
#pragma unroll
            for (int rr = 0; rr < 4; rr++)
                Ct[(rl + rr) * 72 + j * 16 + fr] = f2bf(acc[i][j][rr] + bv[j]);
        }
    }
    __syncthreads();
#pragma unroll
    for (int s_ = 0; s_ < 4; s_++) {
        int u = s_ * 512 + t;
        int rl = u >> 3, seg = u & 7;
        int grow = rbase + rl;
        if (grow < M)
            *(uint4*)(outb + (size_t)pose[grow] * Df + cb + seg * 8) =
                *(const uint4*)&Ct[rl * 72 + seg * 8];
    }
}

extern "C" void kernel_launch(void* const* d_in, const int* in_sizes, int n_in,
                              void* d_out, int out_size, void* d_ws, size_t ws_size,
                              hipStream_t stream) {
    const float* x = (const float*)d_in[0];
    const float* ea = (const float*)d_in[1];
    const float* gamma = (const float*)d_in[2];
    const float* beta = (const float*)d_in[3];
    const float* epsp = (const float*)d_in[4];
    const float* W_edge = (const float*)d_in[5];
    const float* b_edge = (const float*)d_in[6];
    const float* W1 = (const float*)d_in[7];
    const float* b1 = (const float*)d_in[8];
    const float* W2 = (const float*)d_in[9];
    const float* b2 = (const float*)d_in[10];
    const int* eidx = (const int*)d_in[11];
    float* out = (float*)d_out;
    const int N = in_sizes[0] / Df;
    const int E = in_sizes[1] / Df;
    const int* esrc = eidx;
    const int* edst = eidx + E;

    char* w = (char*)d_ws;
    size_t off_ = 0;
    auto alloc = [&](size_t bytes) { char* p = w + off_; off_ += (bytes + 255) & ~(size_t)255; return p; };
    float* stats = (float*)alloc(2 * Df * sizeof(float));
    float* coef = (float*)alloc(2 * Df * sizeof(float));
    unsigned short* hb = (unsigned short*)alloc((size_t)N * Df * 2);
    unsigned short* zb = (unsigned short*)alloc((size_t)N * Df * 2);
    unsigned short* tb = (unsigned short*)alloc((size_t)N * Hf * 2);
    unsigned short* WeT = (unsigned short*)alloc((size_t)Df * Df * 2);
    unsigned short* W1T = (unsigned short*)alloc((size_t)Df * Hf * 2);
    unsigned short* W2T = (unsigned short*)alloc((size_t)Hf * Df * 2);
    int* deg = (int*)alloc((size_t)(N + 1) * 4);      // reused as fill cursor
    int* offs = (int*)alloc((size_t)(N + 1) * 4);
    int* srcp = (int*)alloc((size_t)E * 4);
    int* pose = (int*)alloc((size_t)E * 4);
    int* sums = (int*)alloc(64 * 4);
    size_t msgl_bytes = (size_t)E * Df * 2;
    unsigned short* msgl;
    if (off_ + msgl_bytes <= ws_size) msgl = (unsigned short*)alloc(msgl_bytes);
    else msgl = (unsigned short*)d_out;   // dead until final GEMM writes it
    (void)n_in; (void)out_size;

    hipMemsetAsync(stats, 0, 2 * Df * sizeof(float), stream);
    hipMemsetAsync(deg, 0, (size_t)N * 4, stream);

    // BN + h
    bn_stats<<<1024, 192, 0, stream>>>(x, stats, N);
    bn_finalize<<<1, Df, 0, stream>>>(stats, gamma, beta, coef, N);
    int tot8 = N * Df / 8;
    h_kernel<<<(tot8 + 255) / 256, 256, 0, stream>>>(x, coef, hb, tot8);

    // weights (one dispatch)
    wtrans3<<<(Df * Df + 2 * Df * Hf + 255) / 256, 256, 0, stream>>>(
        W_edge, W1, W2, WeT, W1T, W2T);

    // CSR by dst
    int nb = (N + SCAN_CH - 1) / SCAN_CH;
    degree_k<<<(E + 255) / 256, 256, 0, stream>>>(edst, deg, E);
    scan1<<<nb, 256, 0, stream>>>(deg, offs, sums, N);
    scan2<<<1, 1, 0, stream>>>(sums, nb);
    scan3<<<(N + 256) / 256, 256, 0, stream>>>(offs, sums, N, nb);
    hipMemcpyAsync(deg, offs, (size_t)N * 4, hipMemcpyDeviceToDevice, stream);
    fill_k<<<(E + 255) / 256, 256, 0, stream>>>(edst, esrc, deg, srcp, pose, E);

    // edge linear (strip-512, f32 A): msgl[pose[e]] = ea[e] @ We^T + b_edge
    int estrips = (E + 255) / 256;
    gemm_edge<<<dim3(estrips * 6), 512, 0, stream>>>(ea, WeT, b_edge, pose, msgl, E);

    // gather-reduce -> z (bf16)
    aggregate<<<2048, 256, 0, stream>>>(msgl, hb, offs, srcp, epsp, zb, N);

    // GEMM1 (strip-512): tb = bf16(gelu(zb @ W1T^T + b1))
    int strips = (N + 255) / 256;
    gemm_strip<Df, 1><<<dim3(strips * (Hf / 64)), 512, 0, stream>>>(
        zb, W1T, b1, tb, nullptr, nullptr, N, Hf / 64, Hf);

    // GEMM2 (strip-512, K=768 two halves): out = x + gelu(tb @ W2T^T + b2)
    gemm_strip<Hf, 2><<<dim3(strips * (Df / 64)), 512, 0, stream>>>(
        tb, W2T, b2, nullptr, x, out, N, Df / 64, Df);
}